// Round 14
// baseline (175.167 us; speedup 1.0000x reference)
//
#include <hip/hip_runtime.h>
#include <stdint.h>

typedef short bf16x8 __attribute__((ext_vector_type(8)));
typedef float f32x4 __attribute__((ext_vector_type(4)));

#define DEV __device__ __forceinline__

static constexpr int BB = 2, NN = 2048, DD = 1024, HH = 16, DH = 64;
static constexpr float SCLOG2E = 0.18033688011112042f; // DH^-0.5 * log2(e)

// ---- workspace layout (bytes) ----
static constexpr size_t OFF_PACK   = 1024;
static constexpr size_t PACK_BYTES = (size_t)BB * NN * (NN / 64) * 8ull; // 1MB
static constexpr size_t OFF_WT     = OFF_PACK + PACK_BYTES;
static constexpr size_t WT_ONE     = (size_t)DD * DD;
static constexpr size_t HEAD_BYTES = (size_t)BB * HH * NN * DH * 2ull;   // 8MB
static constexpr size_t OFF_QH     = OFF_WT + 4 * WT_ONE * 2;
static constexpr size_t OFF_KH     = OFF_QH + HEAD_BYTES;
static constexpr size_t OFF_VT     = OFF_KH + HEAD_BYTES;
static constexpr size_t OFF_X      = OFF_VT + HEAD_BYTES;
static constexpr size_t OFF_KB     = OFF_X + HEAD_BYTES;
static constexpr size_t OFF_VB     = OFF_KB + HEAD_BYTES;
static constexpr size_t NEED_BIG   = OFF_VB + HEAD_BYTES;  // ~59.8MB

DEV unsigned short f2b(float f) {                  // fp32 -> bf16 RNE
  unsigned int u = __builtin_bit_cast(unsigned int, f);
  u = (u + 0x7fffu + ((u >> 16) & 1u)) >> 16;
  return (unsigned short)u;
}

#define GLOAD16(gp, lp) __builtin_amdgcn_global_load_lds(                     \
    (const __attribute__((address_space(1))) void*)(gp),                      \
    (__attribute__((address_space(3))) void*)(lp), 16, 0, 0)

// ================= fused prep: transpose_w | cvt_qkv | pack_mask ===========
__global__ __launch_bounds__(256) void prep(
    const float* W0, const float* W1, const float* W2, const float* W3,
    unsigned short* wt,
    const float* q, const float* k, const float* v,
    unsigned short* qb, unsigned short* kb, unsigned short* vb, int doCvt,
    const void* msrc, unsigned long long* packed) {
  __shared__ unsigned short T[64][72];
  const int id = blockIdx.x, t = threadIdx.x;

  if (id < 1024) {                       // ---- transpose_w role
    int z = id >> 8, local = id & 255;
    int n0 = (local & 15) * 64, k0 = (local >> 4) * 64;
    const float* W = (z == 0) ? W0 : (z == 1) ? W1 : (z == 2) ? W2 : W3;
    unsigned short* dst = wt + (size_t)z * WT_ONE;
    #pragma unroll
    for (int i = 0; i < 4; i++) {
      int row = i * 16 + (t >> 4), col = 4 * (t & 15);
      float4 vv = *(const float4*)&W[(size_t)(k0 + row) * DD + n0 + col];
      T[row][col + 0] = f2b(vv.x); T[row][col + 1] = f2b(vv.y);
      T[row][col + 2] = f2b(vv.z); T[row][col + 3] = f2b(vv.w);
    }
    __syncthreads();
    #pragma unroll
    for (int i = 0; i < 4; i++) {
      int n = i * 16 + (t >> 4), kk = 4 * (t & 15);
      ushort4 o = make_ushort4(T[kk][n], T[kk + 1][n], T[kk + 2][n], T[kk + 3][n]);
      *(ushort4*)&dst[(size_t)(n0 + n) * DD + k0 + kk] = o;
    }
  } else if (id < 7168) {                // ---- cvt role
    if (!doCvt) return;
    int local = id - 1024;
    int z = local / 2048, bx = local % 2048;
    const float* s = (z == 0) ? q : (z == 1) ? k : v;
    unsigned short* d = (z == 0) ? qb : (z == 1) ? kb : vb;
    size_t i = ((size_t)bx * 256 + t) * 8;
    float4 a = *(const float4*)&s[i];
    float4 b2 = *(const float4*)&s[i + 4];
    unsigned short o[8] = {f2b(a.x),  f2b(a.y),  f2b(a.z),  f2b(a.w),
                           f2b(b2.x), f2b(b2.y), f2b(b2.z), f2b(b2.w)};
    *(uint4*)&d[i] = *(const uint4*)o;
  } else {                               // ---- pack_mask role (self-detect)
    unsigned f = 0;
    const unsigned* m32 = (const unsigned*)msrc;
    #pragma unroll
    for (int i = 0; i < 16; i++) {
      unsigned xv = m32[i];
      if (xv != 0u && xv != 1u) f |= 1u;
      if (xv != 0u && xv != 0x3f800000u) f |= 2u;
    }
    int w = (id - 7168) * 256 + t;
    size_t base = (size_t)(w >> 5) * 2048 + (size_t)(w & 31) * 64;
    unsigned long long bits = 0ull;
    if (!(f & 1u)) {                     // int32 storage
      const int4* p = (const int4*)msrc + (base >> 2);
      #pragma unroll
      for (int c = 0; c < 16; c++) {
        int4 qv = p[c];
        if (qv.x) bits |= 1ull << (4 * c + 0);
        if (qv.y) bits |= 1ull << (4 * c + 1);
        if (qv.z) bits |= 1ull << (4 * c + 2);
        if (qv.w) bits |= 1ull << (4 * c + 3);
      }
    } else if (!(f & 2u)) {              // float32 storage
      const float4* p = (const float4*)msrc + (base >> 2);
      #pragma unroll
      for (int c = 0; c < 16; c++) {
        float4 qv = p[c];
        if (qv.x != 0.f) bits |= 1ull << (4 * c + 0);
        if (qv.y != 0.f) bits |= 1ull << (4 * c + 1);
        if (qv.z != 0.f) bits |= 1ull << (4 * c + 2);
        if (qv.w != 0.f) bits |= 1ull << (4 * c + 3);
      }
    } else {                             // uint8/bool storage
      const uint4* p = (const uint4*)((const char*)msrc + base);
      #pragma unroll
      for (int c = 0; c < 4; c++) {
        uint4 qv = p[c];
        unsigned vals[4] = {qv.x, qv.y, qv.z, qv.w};
        #pragma unroll
        for (int i = 0; i < 4; i++)
          #pragma unroll
          for (int j = 0; j < 4; j++)
            if ((vals[i] >> (8 * j)) & 0xffu) bits |= 1ull << (16 * c + 4 * i + j);
      }
    }
    packed[w] = bits;
  }
}

// ================= pipelined GEMM (2-phase dbuf, counted vmcnt) ============
template <int PROJ>
__global__ __launch_bounds__(256) void gemm_pl(
    const unsigned short* A0, const unsigned short* A1,
    const unsigned short* A2, const unsigned short* Wt,
    const float* b0, const float* b1, const float* b2, const float* b3,
    unsigned short* dQ, unsigned short* dK, unsigned short* dVt, float* out) {
  __shared__ unsigned short Al[2][128 * 32];
  __shared__ unsigned short Bl[2][128 * 32];
  const int t = threadIdx.x;
  const int w = t >> 6, l = t & 63, lr = l & 15, lg = l >> 4;
  const int wm = (w >> 1) * 64, wn = (w & 1) * 64;

  const int wg = blockIdx.x;
  const int chunk = wg & 7, local = wg >> 3;
  const int colBlk = local >> 2, rowBlk = chunk * 4 + (local & 3);
  const int m0 = rowBlk * 128, n0 = colBlk * 128;
  const int z = PROJ ? 3 : (n0 >> 10);
  const int n0z = PROJ ? n0 : (n0 & 1023);
  const unsigned short* Asrc = PROJ ? A0 : (z == 0 ? A0 : (z == 1 ? A1 : A2));
  const unsigned short* Bsrc = Wt + (size_t)z * WT_ONE;
  const float* bias = PROJ ? b3 : (z == 0 ? b0 : (z == 1 ? b1 : b2));

  const unsigned short* aP =
      Asrc + (size_t)(m0 + w * 32 + (l >> 2)) * DD + (l & 3) * 8;
  const unsigned short* bP =
      Bsrc + (size_t)(n0z + w * 32 + (l >> 2)) * DD + (l & 3) * 8;

  f32x4 acc[4][4];
  #pragma unroll
  for (int i = 0; i < 4; i++)
    #pragma unroll
    for (int j = 0; j < 4; j++) acc[i][j] = (f32x4){0.f, 0.f, 0.f, 0.f};

  auto STAGE = [&](int k0, int buf) {
    GLOAD16(aP + k0,           &Al[buf][(w * 32) * 32]);
    GLOAD16(aP + k0 + 16 * DD, &Al[buf][(w * 32 + 16) * 32]);
    GLOAD16(bP + k0,           &Bl[buf][(w * 32) * 32]);
    GLOAD16(bP + k0 + 16 * DD, &Bl[buf][(w * 32 + 16) * 32]);
  };

  STAGE(0, 0);
  for (int it = 0; it < DD / 32; ++it) {
    if (it + 1 < DD / 32) {
      STAGE((it + 1) * 32, (it + 1) & 1);
      asm volatile("s_waitcnt vmcnt(4)" ::: "memory");
    } else {
      asm volatile("s_waitcnt vmcnt(0)" ::: "memory");
    }
    __builtin_amdgcn_s_barrier();

    const int buf = it & 1;
    bf16x8 af[4], bfr[4];
    #pragma unroll
    for (int mi = 0; mi < 4; mi++)
      af[mi] = *(const bf16x8*)&Al[buf][(wm + mi * 16 + lr) * 32 + lg * 8];
    #pragma unroll
    for (int ni = 0; ni < 4; ni++)
      bfr[ni] = *(const bf16x8*)&Bl[buf][(wn + ni * 16 + lr) * 32 + lg * 8];
    #pragma unroll
    for (int mi = 0; mi < 4; mi++)
      #pragma unroll
      for (int ni = 0; ni < 4; ni++)
        acc[mi][ni] = __builtin_amdgcn_mfma_f32_16x16x32_bf16(
            af[mi], bfr[ni], acc[mi][ni], 0, 0, 0);
    __builtin_amdgcn_s_barrier();
  }

  const float scl = (!PROJ && z == 0) ? SCLOG2E : 1.0f;
  #pragma unroll
  for (int mi = 0; mi < 4; mi++) {
    #pragma unroll
    for (int ni = 0; ni < 4; ni++) {
      int col = n0z + wn + ni * 16 + lr;
      float bv = bias[col];
      int h = col >> 6, dh = col & 63;
      int mbase = m0 + wm + mi * 16 + lg * 4;
      if (PROJ) {
        #pragma unroll
        for (int r = 0; r < 4; r++)
          out[(size_t)(mbase + r) * DD + col] = acc[mi][ni][r] + bv;
      } else if (z == 2) {
        int bq = mbase >> 11, n = mbase & 2047;
        unsigned short o4[4];
        #pragma unroll
        for (int r = 0; r < 4; r++) o4[r] = f2b(acc[mi][ni][r] + bv);
        *(ushort4*)&dVt[(((size_t)(bq * HH + h)) * DH + dh) * NN + n] =
            *(const ushort4*)o4;
      } else {
        unsigned short* dst = (z == 0) ? dQ : dK;
        #pragma unroll
        for (int r = 0; r < 4; r++) {
          int m = mbase + r;
          int bq = m >> 11, n = m & 2047;
          dst[(((size_t)(bq * HH + h)) * NN + n) * DH + dh] =
              f2b((acc[mi][ni][r] + bv) * scl);
        }
      }
    }
  }
}

// ================= fallback QKV GEMM (fp32 A, non-pipelined) ===============
__global__ __launch_bounds__(256) void gemm_qkv_f32(
    const float* A0, const float* A1, const float* A2,
    const unsigned short* Wt,
    const float* b0, const float* b1, const float* b2,
    unsigned short* dQ, unsigned short* dK, unsigned short* dVt) {
  __shared__ unsigned short Al[128 * 32];
  __shared__ unsigned short Bl[128 * 32];
  const int t = threadIdx.x, z = blockIdx.z;
  const int m0 = blockIdx.y * 128, n0 = blockIdx.x * 128;
  const unsigned short* Bsrc = Wt + (size_t)z * WT_ONE;
  const float* Af = (z == 0) ? A0 : (z == 1) ? A1 : A2;
  const float* bias = (z == 0) ? b0 : (z == 1) ? b1 : b2;
  const int w = t >> 6, l = t & 63, lr = l & 15, lg = l >> 4;
  const int wm = (w >> 1) * 64, wn = (w & 1) * 64;

  f32x4 acc[4][4];
  #pragma unroll
  for (int i = 0; i < 4; i++)
    #pragma unroll
    for (int j = 0; j < 4; j++) acc[i][j] = (f32x4){0.f, 0.f, 0.f, 0.f};

  for (int k0 = 0; k0 < DD; k0 += 32) {
    __syncthreads();
    #pragma unroll
    for (int i = 0; i < 4; i++) {
      int row = i * 32 + (t >> 3), kk = 4 * (t & 7);
      float4 vv = *(const float4*)&Af[(size_t)(m0 + row) * DD + k0 + kk];
      ushort4 o4 = make_ushort4(f2b(vv.x), f2b(vv.y), f2b(vv.z), f2b(vv.w));
      *(ushort4*)&Al[row * 32 + kk] = o4;
    }
    #pragma unroll
    for (int c = 0; c < 2; c++)
      GLOAD16(&Bsrc[(size_t)(n0 + w * 32 + c * 16 + (l >> 2)) * DD + k0 + (l & 3) * 8],
              &Bl[(w * 32 + c * 16) * 32]);
    __syncthreads();

    bf16x8 af[4], bfr[4];
    #pragma unroll
    for (int mi = 0; mi < 4; mi++)
      af[mi] = *(const bf16x8*)&Al[(wm + mi * 16 + lr) * 32 + lg * 8];
    #pragma unroll
    for (int ni = 0; ni < 4; ni++)
      bfr[ni] = *(const bf16x8*)&Bl[(wn + ni * 16 + lr) * 32 + lg * 8];
    #pragma unroll
    for (int mi = 0; mi < 4; mi++)
      #pragma unroll
      for (int ni = 0; ni < 4; ni++)
        acc[mi][ni] = __builtin_amdgcn_mfma_f32_16x16x32_bf16(
            af[mi], bfr[ni], acc[mi][ni], 0, 0, 0);
  }

  const float scl = (z == 0) ? SCLOG2E : 1.0f;
  #pragma unroll
  for (int mi = 0; mi < 4; mi++) {
    #pragma unroll
    for (int ni = 0; ni < 4; ni++) {
      int col = n0 + wn + ni * 16 + lr;
      float bv = bias[col];
      int h = col >> 6, dh = col & 63;
      int mbase = m0 + wm + mi * 16 + lg * 4;
      if (z == 2) {
        int bq = mbase >> 11, n = mbase & 2047;
        unsigned short o4[4];
        #pragma unroll
        for (int r = 0; r < 4; r++) o4[r] = f2b(acc[mi][ni][r] + bv);
        *(ushort4*)&dVt[(((size_t)(bq * HH + h)) * DH + dh) * NN + n] =
            *(const ushort4*)o4;
      } else {
        unsigned short* dst = (z == 0) ? dQ : dK;
        #pragma unroll
        for (int r = 0; r < 4; r++) {
          int m = mbase + r;
          int bq = m >> 11, n = m & 2047;
          dst[(((size_t)(bq * HH + h)) * NN + n) * DH + dh] =
              f2b((acc[mi][ni][r] + bv) * scl);
        }
      }
    }
  }
}

// ================= flash attention, KVBLK=128, named-scalar prefetch =======
// 4 waves x 16 q-rows. K[128][64] + V^T[64][128] staged per 128-k tile -> one
// barrier pair + one staging burst per 128 k (round 8 schedule), but ALL
// prefetch state in individually named scalars (rule #20: arrays spilled to
// scratch in round 8 -> 437MB WRITE_SIZE; named uint4s stay in VGPRs).
// Per-subtile math byte-identical to the round-13 proven body.
__global__ __launch_bounds__(256) void attn_k(
    const unsigned short* qh, const unsigned short* kh,
    const unsigned short* vht, const unsigned long long* packed,
    unsigned short* x) {
  __shared__ __align__(16) unsigned short Kl[128 * 64];    // rows 128B, swz
  __shared__ __align__(16) unsigned short Vl[64 * 128];    // rows 256B, swz
  __shared__ __align__(16) unsigned short Pl[4][16 * 64];  // per-wave strip
  char* KlB = (char*)Kl;
  char* VlB = (char*)Vl;
  const int t = threadIdx.x, w = t >> 6, l = t & 63;
  const int lr = l & 15, lg = l >> 4;
  char* PlB = (char*)&Pl[w][0];

  const int id = blockIdx.x;            // 0..1023
  const int xcd = id & 7, j = id >> 3;
  const int bhg = xcd * 4 + (j >> 5);
  const int q0 = (j & 31) * 64;
  const int b = bhg >> 4, h = bhg & 15;
  const size_t bh = (size_t)b * HH + h;
  const unsigned short* Q = qh + bh * (size_t)NN * DH;
  const unsigned short* K = kh + bh * (size_t)NN * DH;
  const unsigned short* V = vht + bh * (size_t)NN * DH;   // [dh][n]
  const int qrow = q0 + w * 16 + lr;
  const unsigned long long* pmrow =
      packed + ((size_t)b * NN + qrow) * (NN / 64);

  bf16x8 qf[2];
  #pragma unroll
  for (int kc = 0; kc < 2; kc++)
    qf[kc] = *(const bf16x8*)&Q[(size_t)qrow * DH + kc * 32 + lg * 8];

  f32x4 o[4];
  #pragma unroll
  for (int f = 0; f < 4; f++) o[f] = (f32x4){0.f, 0.f, 0.f, 0.f};
  float lsum = 0.f;

  // ---- staging geometry (all named scalars) ----
  const int srowK = t >> 1, halfK = t & 1;       // K: 128 rows, 2 threads/row
  const int swrK = (srowK & 7) << 4;
  const int sK0 = srowK * 128 + ((halfK * 64 +  0) ^ swrK);
  const int sK1 = srowK * 128 + ((halfK * 64 + 16) ^ swrK);
  const int sK2 = srowK * 128 + ((halfK * 64 + 32) ^ swrK);
  const int sK3 = srowK * 128 + ((halfK * 64 + 48) ^ swrK);
  const int srowV = t >> 2, qrtV = t & 3;        // V: 64 rows, 4 threads/row
  const int swrV = (srowV & 7) << 4;
  const int cV0 = qrtV * 64 +  0, cV1 = qrtV * 64 + 16;
  const int cV2 = qrtV * 64 + 32, cV3 = qrtV * 64 + 48;
  const int sV0 = srowV * 256 + (cV0 & 128) + ((cV0 & 127) ^ swrV);
  const int sV1 = srowV * 256 + (cV1 & 128) + ((cV1 & 127) ^ swrV);
  const int sV2 = srowV * 256 + (cV2 & 128) + ((cV2 & 127) ^ swrV);
  const int sV3 = srowV * 256 + (cV3 & 128) + ((cV3 & 127) ^ swrV);
  const int swl = (lr & 7) << 4;

  const unsigned short* kpp = &K[(size_t)srowK * DH + halfK * 32];
  const unsigned short* vpp = &V[(size_t)srowV * NN + qrtV * 32];
  uint4 kr0 = *(const uint4*)(kpp +  0), kr1 = *(const uint4*)(kpp +  8);
  uint4 kr2 = *(const uint4*)(kpp + 16), kr3 = *(const uint4*)(kpp + 24);
  uint4 vr0 = *(const uint4*)(vpp +  0), vr1 = *(const uint4*)(vpp +  8);
  uint4 vr2 = *(const uint4*)(vpp + 16), vr3 = *(const uint4*)(vpp + 24);
  unsigned long long mwa = pmrow[0], mwb = pmrow[1];

  // per-64k subtile body (s = literal 0/1; byte-identical math to round 13)
  auto sub = [&](int s, unsigned long long mw) {
    f32x4 sv4[4];
    __builtin_amdgcn_s_setprio(1);
    #pragma unroll
    for (int f = 0; f < 4; f++) {
      f32x4 sx = (f32x4){0.f, 0.f, 0.f, 0.f};
      const int rb = (s * 64 + 16 * f + lr) * 128;
      bf16x8 kf0 = *(const bf16x8*)&KlB[rb + ((lg * 16) ^ swl)];
      bf16x8 kf1 = *(const bf16x8*)&KlB[rb + ((64 + lg * 16) ^ swl)];
      sx = __builtin_amdgcn_mfma_f32_16x16x32_bf16(kf0, qf[0], sx, 0, 0, 0);
      sx = __builtin_amdgcn_mfma_f32_16x16x32_bf16(kf1, qf[1], sx, 0, 0, 0);
      sv4[f] = sx;
    }
    __builtin_amdgcn_s_setprio(0);

    float part = 0.f;
    #pragma unroll
    for (int f = 0; f < 4; f++) {
      unsigned nib = (unsigned)(mw >> (16 * f + 4 * lg)) & 0xFu;
      float pv[4];
      #pragma unroll
      for (int r = 0; r < 4; r++) {
        float sc = ((nib >> r) & 1u) ? -30000.f : sv4[f][r];
        pv[r] = __builtin_amdgcn_exp2f(sc);
        part += pv[r];
      }
      unsigned w0, w1;
      asm("v_cvt_pk_bf16_f32 %0, %1, %2" : "=v"(w0) : "v"(pv[0]), "v"(pv[1]));
      asm("v_cvt_pk_bf16_f32 %0, %1, %2" : "=v"(w1) : "v"(pv[2]), "v"(pv[3]));
      *(uint2*)&PlB[lr * 128 + ((f * 32 + lg * 8) ^ swl)] = make_uint2(w0, w1);
    }
    lsum += part;
    asm volatile("s_waitcnt lgkmcnt(0)" ::: "memory");
    __builtin_amdgcn_sched_barrier(0);

    bf16x8 pf0 = *(const bf16x8*)&PlB[lr * 128 + ((lg * 16) ^ swl)];
    bf16x8 pf1 = *(const bf16x8*)&PlB[lr * 128 + ((64 + lg * 16) ^ swl)];
    __builtin_amdgcn_s_setprio(1);
    #pragma unroll
    for (int f = 0; f < 4; f++) {
      const int rb = (16 * f + lr) * 256 + s * 128;
      bf16x8 vf0 = *(const bf16x8*)&VlB[rb + ((lg * 16) ^ swl)];
      o[f] = __builtin_amdgcn_mfma_f32_16x16x32_bf16(vf0, pf0, o[f], 0, 0, 0);
      bf16x8 vf1 = *(const bf16x8*)&VlB[rb + ((64 + lg * 16) ^ swl)];
      o[f] = __builtin_amdgcn_mfma_f32_16x16x32_bf16(vf1, pf1, o[f], 0, 0, 0);
    }
    __builtin_amdgcn_s_setprio(0);
  };

  for (int kt = 0; kt < NN / 128; kt++) {
    __syncthreads();
    *(uint4*)&KlB[sK0] = kr0;
    *(uint4*)&KlB[sK1] = kr1;
    *(uint4*)&KlB[sK2] = kr2;
    *(uint4*)&KlB[sK3] = kr3;
    *(uint4*)&VlB[sV0] = vr0;
    *(uint4*)&VlB[sV1] = vr1;
    *(uint4*)&VlB[sV2] = vr2;
    *(uint4*)&VlB[sV3] = vr3;
    __syncthreads();
    unsigned long long mwaN = mwa, mwbN = mwb;
    if (kt + 1 < NN / 128) {                   // prefetch next 128-tile
      kpp += 128 * DH;
      vpp += 128;
      kr0 = *(const uint4*)(kpp +  0); kr1 = *(const uint4*)(kpp +  8);
      kr2 = *(const uint4*)(kpp + 16); kr3 = *(const uint4*)(kpp + 24);
      vr0 = *(const uint4*)(vpp +  0); vr1 = *(const uint4*)(vpp +  8);
      vr2 = *(const uint4*)(vpp + 16); vr3 = *(const uint4*)(vpp + 24);
      mwaN = pmrow[2 * kt + 2];
      mwbN = pmrow[2 * kt + 3];
    }

    sub(0, mwa);
    sub(1, mwb);

    mwa = mwaN;
    mwb = mwbN;
  }

  lsum += __shfl_xor(lsum, 16);
  lsum += __shfl_xor(lsum, 32);
  float inv = 1.f / fmaxf(lsum, 1e-30f);
  #pragma unroll
  for (int f = 0; f < 4; f++) {
    unsigned w0, w1;
    float a0 = o[f][0] * inv, a1 = o[f][1] * inv;
    float a2 = o[f][2] * inv, a3 = o[f][3] * inv;
    asm("v_cvt_pk_bf16_f32 %0, %1, %2" : "=v"(w0) : "v"(a0), "v"(a1));
    asm("v_cvt_pk_bf16_f32 %0, %1, %2" : "=v"(w1) : "v"(a2), "v"(a3));
    *(uint2*)&x[((size_t)b * NN + qrow) * DD + h * DH + 16 * f + lg * 4] =
        make_uint2(w0, w1);
  }
}

extern "C" void kernel_launch(void* const* d_in, const int* in_sizes, int n_in,
                              void* d_out, int out_size, void* d_ws, size_t ws_size,
                              hipStream_t stream) {
  const float* q  = (const float*)d_in[0];
  const float* k  = (const float*)d_in[1];
  const float* v  = (const float*)d_in[2];
  const void*  mk = d_in[3];
  const float* Wq = (const float*)d_in[4];
  const float* bq = (const float*)d_in[5];
  const float* Wk = (const float*)d_in[6];
  const float* bk = (const float*)d_in[7];
  const float* Wv = (const float*)d_in[8];
  const float* bv = (const float*)d_in[9];
  const float* Wp = (const float*)d_in[10];
  const float* bp = (const float*)d_in[11];
  float* out = (float*)d_out;
  char* ws = (char*)d_ws;

  unsigned long long* packed = (unsigned long long*)(ws + OFF_PACK);
  unsigned short* wt  = (unsigned short*)(ws + OFF_WT);
  unsigned short* qhp = (unsigned short*)(ws + OFF_QH);
  unsigned short* khp = (unsigned short*)(ws + OFF_KH);
  unsigned short* vht = (unsigned short*)(ws + OFF_VT);
  unsigned short* x   = (unsigned short*)(ws + OFF_X);
  unsigned short* qb  = (unsigned short*)(ws + OFF_X);  // alias: dead before attn
  unsigned short* kb  = (unsigned short*)(ws + OFF_KB);
  unsigned short* vb  = (unsigned short*)(ws + OFF_VB);

  const bool big = ws_size >= NEED_BIG;

  prep<<<dim3(7680), 256, 0, stream>>>(Wq, Wk, Wv, Wp, wt, q, k, v,
                                       qb, kb, vb, big ? 1 : 0, mk, packed);
  if (big) {
    gemm_pl<0><<<dim3(768), 256, 0, stream>>>(qb, kb, vb, wt,
                                              bq, bk, bv, bp,
                                              qhp, khp, vht, nullptr);
  } else {
    gemm_qkv_f32<<<dim3(8, 32, 3), 256, 0, stream>>>(q, k, v, wt, bq, bk, bv,
                                                     qhp, khp, vht);
  }
  attn_k<<<dim3(1024), 256, 0, stream>>>(qhp, khp, vht, packed, x);
  gemm_pl<1><<<dim3(256), 256, 0, stream>>>(x, nullptr, nullptr, wt,
                                            bq, bk, bv, bp,
                                            nullptr, nullptr, nullptr, out);
}

// Round 15
// 162.999 us; speedup vs baseline: 1.0746x; 1.0746x over previous
//
#include <hip/hip_runtime.h>
#include <stdint.h>

typedef short bf16x8 __attribute__((ext_vector_type(8)));
typedef float f32x4 __attribute__((ext_vector_type(4)));

#define DEV __device__ __forceinline__

static constexpr int BB = 2, NN = 2048, DD = 1024, HH = 16, DH = 64;
static constexpr float SCLOG2E = 0.18033688011112042f; // DH^-0.5 * log2(e)

// ---- workspace layout (bytes) ----
static constexpr size_t OFF_PACK   = 1024;
static constexpr size_t PACK_BYTES = (size_t)BB * NN * (NN / 64) * 8ull; // 1MB
static constexpr size_t OFF_WT     = OFF_PACK + PACK_BYTES;
static constexpr size_t WT_ONE     = (size_t)DD * DD;
static constexpr size_t HEAD_BYTES = (size_t)BB * HH * NN * DH * 2ull;   // 8MB
static constexpr size_t OFF_QH     = OFF_WT + 4 * WT_ONE * 2;
static constexpr size_t OFF_KH     = OFF_QH + HEAD_BYTES;
static constexpr size_t OFF_VT     = OFF_KH + HEAD_BYTES;
static constexpr size_t OFF_X      = OFF_VT + HEAD_BYTES;
static constexpr size_t OFF_KB     = OFF_X + HEAD_BYTES;
static constexpr size_t OFF_VB     = OFF_KB + HEAD_BYTES;
static constexpr size_t NEED_BIG   = OFF_VB + HEAD_BYTES;  // ~59.8MB

DEV unsigned short f2b(float f) {                  // fp32 -> bf16 RNE
  unsigned int u = __builtin_bit_cast(unsigned int, f);
  u = (u + 0x7fffu + ((u >> 16) & 1u)) >> 16;
  return (unsigned short)u;
}

#define GLOAD16(gp, lp) __builtin_amdgcn_global_load_lds(                     \
    (const __attribute__((address_space(1))) void*)(gp),                      \
    (__attribute__((address_space(3))) void*)(lp), 16, 0, 0)

// ================= fused prep: transpose_w | cvt_qkv | pack_mask ===========
__global__ __launch_bounds__(256) void prep(
    const float* W0, const float* W1, const float* W2, const float* W3,
    unsigned short* wt,
    const float* q, const float* k, const float* v,
    unsigned short* qb, unsigned short* kb, unsigned short* vb, int doCvt,
    const void* msrc, unsigned long long* packed) {
  __shared__ unsigned short T[64][72];
  const int id = blockIdx.x, t = threadIdx.x;

  if (id < 1024) {                       // ---- transpose_w role
    int z = id >> 8, local = id & 255;
    int n0 = (local & 15) * 64, k0 = (local >> 4) * 64;
    const float* W = (z == 0) ? W0 : (z == 1) ? W1 : (z == 2) ? W2 : W3;
    unsigned short* dst = wt + (size_t)z * WT_ONE;
    #pragma unroll
    for (int i = 0; i < 4; i++) {
      int row = i * 16 + (t >> 4), col = 4 * (t & 15);
      float4 vv = *(const float4*)&W[(size_t)(k0 + row) * DD + n0 + col];
      T[row][col + 0] = f2b(vv.x); T[row][col + 1] = f2b(vv.y);
      T[row][col + 2] = f2b(vv.z); T[row][col + 3] = f2b(vv.w);
    }
    __syncthreads();
    #pragma unroll
    for (int i = 0; i < 4; i++) {
      int n = i * 16 + (t >> 4), kk = 4 * (t & 15);
      ushort4 o = make_ushort4(T[kk][n], T[kk + 1][n], T[kk + 2][n], T[kk + 3][n]);
      *(ushort4*)&dst[(size_t)(n0 + n) * DD + k0 + kk] = o;
    }
  } else if (id < 7168) {                // ---- cvt role
    if (!doCvt) return;
    int local = id - 1024;
    int z = local / 2048, bx = local % 2048;
    const float* s = (z == 0) ? q : (z == 1) ? k : v;
    unsigned short* d = (z == 0) ? qb : (z == 1) ? kb : vb;
    size_t i = ((size_t)bx * 256 + t) * 8;
    float4 a = *(const float4*)&s[i];
    float4 b2 = *(const float4*)&s[i + 4];
    unsigned short o[8] = {f2b(a.x),  f2b(a.y),  f2b(a.z),  f2b(a.w),
                           f2b(b2.x), f2b(b2.y), f2b(b2.z), f2b(b2.w)};
    *(uint4*)&d[i] = *(const uint4*)o;
  } else {                               // ---- pack_mask role (self-detect)
    unsigned f = 0;
    const unsigned* m32 = (const unsigned*)msrc;
    #pragma unroll
    for (int i = 0; i < 16; i++) {
      unsigned xv = m32[i];
      if (xv != 0u && xv != 1u) f |= 1u;
      if (xv != 0u && xv != 0x3f800000u) f |= 2u;
    }
    int w = (id - 7168) * 256 + t;
    size_t base = (size_t)(w >> 5) * 2048 + (size_t)(w & 31) * 64;
    unsigned long long bits = 0ull;
    if (!(f & 1u)) {                     // int32 storage
      const int4* p = (const int4*)msrc + (base >> 2);
      #pragma unroll
      for (int c = 0; c < 16; c++) {
        int4 qv = p[c];
        if (qv.x) bits |= 1ull << (4 * c + 0);
        if (qv.y) bits |= 1ull << (4 * c + 1);
        if (qv.z) bits |= 1ull << (4 * c + 2);
        if (qv.w) bits |= 1ull << (4 * c + 3);
      }
    } else if (!(f & 2u)) {              // float32 storage
      const float4* p = (const float4*)msrc + (base >> 2);
      #pragma unroll
      for (int c = 0; c < 16; c++) {
        float4 qv = p[c];
        if (qv.x != 0.f) bits |= 1ull << (4 * c + 0);
        if (qv.y != 0.f) bits |= 1ull << (4 * c + 1);
        if (qv.z != 0.f) bits |= 1ull << (4 * c + 2);
        if (qv.w != 0.f) bits |= 1ull << (4 * c + 3);
      }
    } else {                             // uint8/bool storage
      const uint4* p = (const uint4*)((const char*)msrc + base);
      #pragma unroll
      for (int c = 0; c < 4; c++) {
        uint4 qv = p[c];
        unsigned vals[4] = {qv.x, qv.y, qv.z, qv.w};
        #pragma unroll
        for (int i = 0; i < 4; i++)
          #pragma unroll
          for (int j = 0; j < 4; j++)
            if ((vals[i] >> (8 * j)) & 0xffu) bits |= 1ull << (16 * c + 4 * i + j);
      }
    }
    packed[w] = bits;
  }
}

// ================= pipelined GEMM (2-phase dbuf, counted vmcnt) ============
// PROJ=0: fused QKV, 1D grid 768 = 24 colBlk x 32 rowBlk, XCD-chunked.
//         z = colBlk/8 selects A (qb/kb/vb), W, bias, dest (Q/K scaled, V^T).
// PROJ=1: out-projection, 1D grid 256 = 8 colBlk x 32 rowBlk. fp32 out+bias.
template <int PROJ>
__global__ __launch_bounds__(256) void gemm_pl(
    const unsigned short* A0, const unsigned short* A1,
    const unsigned short* A2, const unsigned short* Wt,
    const float* b0, const float* b1, const float* b2, const float* b3,
    unsigned short* dQ, unsigned short* dK, unsigned short* dVt, float* out) {
  __shared__ unsigned short Al[2][128 * 32];
  __shared__ unsigned short Bl[2][128 * 32];
  const int t = threadIdx.x;
  const int w = t >> 6, l = t & 63, lr = l & 15, lg = l >> 4;
  const int wm = (w >> 1) * 64, wn = (w & 1) * 64;

  // XCD-chunked swizzle: chunk = wg&7 lands on XCD (round-robin dispatch);
  // each chunk owns 4 row-panels x all col-panels -> A L2-resident.
  const int wg = blockIdx.x;
  const int chunk = wg & 7, local = wg >> 3;
  const int colBlk = local >> 2, rowBlk = chunk * 4 + (local & 3);
  const int m0 = rowBlk * 128, n0 = colBlk * 128;
  const int z = PROJ ? 3 : (n0 >> 10);
  const int n0z = PROJ ? n0 : (n0 & 1023);
  const unsigned short* Asrc = PROJ ? A0 : (z == 0 ? A0 : (z == 1 ? A1 : A2));
  const unsigned short* Bsrc = Wt + (size_t)z * WT_ONE;
  const float* bias = PROJ ? b3 : (z == 0 ? b0 : (z == 1 ? b1 : b2));

  const unsigned short* aP =
      Asrc + (size_t)(m0 + w * 32 + (l >> 2)) * DD + (l & 3) * 8;
  const unsigned short* bP =
      Bsrc + (size_t)(n0z + w * 32 + (l >> 2)) * DD + (l & 3) * 8;

  f32x4 acc[4][4];
  #pragma unroll
  for (int i = 0; i < 4; i++)
    #pragma unroll
    for (int j = 0; j < 4; j++) acc[i][j] = (f32x4){0.f, 0.f, 0.f, 0.f};

  auto STAGE = [&](int k0, int buf) {
    GLOAD16(aP + k0,           &Al[buf][(w * 32) * 32]);
    GLOAD16(aP + k0 + 16 * DD, &Al[buf][(w * 32 + 16) * 32]);
    GLOAD16(bP + k0,           &Bl[buf][(w * 32) * 32]);
    GLOAD16(bP + k0 + 16 * DD, &Bl[buf][(w * 32 + 16) * 32]);
  };

  STAGE(0, 0);
  for (int it = 0; it < DD / 32; ++it) {
    if (it + 1 < DD / 32) {
      STAGE((it + 1) * 32, (it + 1) & 1);            // prefetch next tile
      asm volatile("s_waitcnt vmcnt(4)" ::: "memory"); // current tile landed
    } else {
      asm volatile("s_waitcnt vmcnt(0)" ::: "memory");
    }
    __builtin_amdgcn_s_barrier();                    // tile visible to all

    const int buf = it & 1;
    bf16x8 af[4], bfr[4];
    #pragma unroll
    for (int mi = 0; mi < 4; mi++)
      af[mi] = *(const bf16x8*)&Al[buf][(wm + mi * 16 + lr) * 32 + lg * 8];
    #pragma unroll
    for (int ni = 0; ni < 4; ni++)
      bfr[ni] = *(const bf16x8*)&Bl[buf][(wn + ni * 16 + lr) * 32 + lg * 8];
    #pragma unroll
    for (int mi = 0; mi < 4; mi++)
      #pragma unroll
      for (int ni = 0; ni < 4; ni++)
        acc[mi][ni] = __builtin_amdgcn_mfma_f32_16x16x32_bf16(
            af[mi], bfr[ni], acc[mi][ni], 0, 0, 0);
    __builtin_amdgcn_s_barrier();                    // reads done -> reusable
  }

  const float scl = (!PROJ && z == 0) ? SCLOG2E : 1.0f;
  #pragma unroll
  for (int mi = 0; mi < 4; mi++) {
    #pragma unroll
    for (int ni = 0; ni < 4; ni++) {
      int col = n0z + wn + ni * 16 + lr;
      float bv = bias[col];
      int h = col >> 6, dh = col & 63;
      int mbase = m0 + wm + mi * 16 + lg * 4;
      if (PROJ) {
        #pragma unroll
        for (int r = 0; r < 4; r++)
          out[(size_t)(mbase + r) * DD + col] = acc[mi][ni][r] + bv;
      } else if (z == 2) {
        int bq = mbase >> 11, n = mbase & 2047;
        unsigned short o4[4];
        #pragma unroll
        for (int r = 0; r < 4; r++) o4[r] = f2b(acc[mi][ni][r] + bv);
        *(ushort4*)&dVt[(((size_t)(bq * HH + h)) * DH + dh) * NN + n] =
            *(const ushort4*)o4;
      } else {
        unsigned short* dst = (z == 0) ? dQ : dK;
        #pragma unroll
        for (int r = 0; r < 4; r++) {
          int m = mbase + r;
          int bq = m >> 11, n = m & 2047;
          dst[(((size_t)(bq * HH + h)) * NN + n) * DH + dh] =
              f2b((acc[mi][ni][r] + bv) * scl);
        }
      }
    }
  }
}

// ================= fallback QKV GEMM (fp32 A, non-pipelined) ===============
__global__ __launch_bounds__(256) void gemm_qkv_f32(
    const float* A0, const float* A1, const float* A2,
    const unsigned short* Wt,
    const float* b0, const float* b1, const float* b2,
    unsigned short* dQ, unsigned short* dK, unsigned short* dVt) {
  __shared__ unsigned short Al[128 * 32];
  __shared__ unsigned short Bl[128 * 32];
  const int t = threadIdx.x, z = blockIdx.z;
  const int m0 = blockIdx.y * 128, n0 = blockIdx.x * 128;
  const unsigned short* Bsrc = Wt + (size_t)z * WT_ONE;
  const float* Af = (z == 0) ? A0 : (z == 1) ? A1 : A2;
  const float* bias = (z == 0) ? b0 : (z == 1) ? b1 : b2;
  const int w = t >> 6, l = t & 63, lr = l & 15, lg = l >> 4;
  const int wm = (w >> 1) * 64, wn = (w & 1) * 64;

  f32x4 acc[4][4];
  #pragma unroll
  for (int i = 0; i < 4; i++)
    #pragma unroll
    for (int j = 0; j < 4; j++) acc[i][j] = (f32x4){0.f, 0.f, 0.f, 0.f};

  for (int k0 = 0; k0 < DD; k0 += 32) {
    __syncthreads();
    #pragma unroll
    for (int i = 0; i < 4; i++) {
      int row = i * 32 + (t >> 3), kk = 4 * (t & 7);
      float4 vv = *(const float4*)&Af[(size_t)(m0 + row) * DD + k0 + kk];
      ushort4 o4 = make_ushort4(f2b(vv.x), f2b(vv.y), f2b(vv.z), f2b(vv.w));
      *(ushort4*)&Al[row * 32 + kk] = o4;
    }
    #pragma unroll
    for (int c = 0; c < 2; c++)
      GLOAD16(&Bsrc[(size_t)(n0 + w * 32 + c * 16 + (l >> 2)) * DD + k0 + (l & 3) * 8],
              &Bl[(w * 32 + c * 16) * 32]);
    __syncthreads();

    bf16x8 af[4], bfr[4];
    #pragma unroll
    for (int mi = 0; mi < 4; mi++)
      af[mi] = *(const bf16x8*)&Al[(wm + mi * 16 + lr) * 32 + lg * 8];
    #pragma unroll
    for (int ni = 0; ni < 4; ni++)
      bfr[ni] = *(const bf16x8*)&Bl[(wn + ni * 16 + lr) * 32 + lg * 8];
    #pragma unroll
    for (int mi = 0; mi < 4; mi++)
      #pragma unroll
      for (int ni = 0; ni < 4; ni++)
        acc[mi][ni] = __builtin_amdgcn_mfma_f32_16x16x32_bf16(
            af[mi], bfr[ni], acc[mi][ni], 0, 0, 0);
  }

  const float scl = (z == 0) ? SCLOG2E : 1.0f;
  #pragma unroll
  for (int mi = 0; mi < 4; mi++) {
    #pragma unroll
    for (int ni = 0; ni < 4; ni++) {
      int col = n0 + wn + ni * 16 + lr;
      float bv = bias[col];
      int h = col >> 6, dh = col & 63;
      int mbase = m0 + wm + mi * 16 + lg * 4;
      if (z == 2) {
        int bq = mbase >> 11, n = mbase & 2047;
        unsigned short o4[4];
        #pragma unroll
        for (int r = 0; r < 4; r++) o4[r] = f2b(acc[mi][ni][r] + bv);
        *(ushort4*)&dVt[(((size_t)(bq * HH + h)) * DH + dh) * NN + n] =
            *(const ushort4*)o4;
      } else {
        unsigned short* dst = (z == 0) ? dQ : dK;
        #pragma unroll
        for (int r = 0; r < 4; r++) {
          int m = mbase + r;
          int bq = m >> 11, n = m & 2047;
          dst[(((size_t)(bq * HH + h)) * NN + n) * DH + dh] =
              f2b((acc[mi][ni][r] + bv) * scl);
        }
      }
    }
  }
}

// ================= flash attention (proven optimum, rounds 7/13) ===========
// 4 waves x 16 q-rows, KVBLK=64, named-scalar reg prefetch, fixed-max exp2
// softmax, packed-bit mask, XOR-swizzled 128B-stride LDS, head-pinned XCD
// swizzle, setprio on MFMA clusters.
__global__ __launch_bounds__(256) void attn_k(
    const unsigned short* qh, const unsigned short* kh,
    const unsigned short* vht, const unsigned long long* packed,
    unsigned short* x) {
  __shared__ __align__(16) unsigned short Kl[64 * 64];
  __shared__ __align__(16) unsigned short Vl[64 * 64];
  __shared__ __align__(16) unsigned short Pl[4][16 * 64];
  char* KlB = (char*)Kl;
  char* VlB = (char*)Vl;
  const int t = threadIdx.x, w = t >> 6, l = t & 63;
  const int lr = l & 15, lg = l >> 4;
  char* PlB = (char*)&Pl[w][0];

  const int id = blockIdx.x;
  const int xcd = id & 7, j = id >> 3;
  const int bhg = xcd * 4 + (j >> 5);
  const int q0 = (j & 31) * 64;
  const int b = bhg >> 4, h = bhg & 15;
  const size_t bh = (size_t)b * HH + h;
  const unsigned short* Q = qh + bh * (size_t)NN * DH;
  const unsigned short* K = kh + bh * (size_t)NN * DH;
  const unsigned short* V = vht + bh * (size_t)NN * DH;
  const int qrow = q0 + w * 16 + lr;
  const unsigned long long* pmrow =
      packed + ((size_t)b * NN + qrow) * (NN / 64);

  bf16x8 qf[2];
  #pragma unroll
  for (int kc = 0; kc < 2; kc++)
    qf[kc] = *(const bf16x8*)&Q[(size_t)qrow * DH + kc * 32 + lg * 8];

  f32x4 o[4];
  #pragma unroll
  for (int f = 0; f < 4; f++) o[f] = (f32x4){0.f, 0.f, 0.f, 0.f};
  float lsum = 0.f;

  const int srow = t >> 2, sc0 = (t & 3) * 32;
  const int swr = (srow & 7) << 4;
  const int swl = (lr & 7) << 4;
  const int sA = srow * 128 + (sc0 ^ swr);
  const int sB = srow * 128 + ((sc0 + 16) ^ swr);

  const unsigned short* kpp = &K[(size_t)srow * DH + sc0 / 2];
  const unsigned short* vpp = &V[(size_t)srow * NN + sc0 / 2];
  uint4 k0r = *(const uint4*)kpp, k1r = *(const uint4*)(kpp + 8);
  uint4 v0r = *(const uint4*)vpp, v1r = *(const uint4*)(vpp + 8);

  for (int kt = 0; kt < NN / 64; kt++) {
    __syncthreads();
    *(uint4*)&KlB[sA] = k0r;
    *(uint4*)&KlB[sB] = k1r;
    *(uint4*)&VlB[sA] = v0r;
    *(uint4*)&VlB[sB] = v1r;
    __syncthreads();
    if (kt + 1 < NN / 64) {
      kpp += 64 * DH;
      vpp += 64;
      k0r = *(const uint4*)kpp;  k1r = *(const uint4*)(kpp + 8);
      v0r = *(const uint4*)vpp;  v1r = *(const uint4*)(vpp + 8);
    }

    unsigned long long mw = pmrow[kt];

    f32x4 sv4[4];
    __builtin_amdgcn_s_setprio(1);
    #pragma unroll
    for (int f = 0; f < 4; f++) {
      f32x4 s = (f32x4){0.f, 0.f, 0.f, 0.f};
      bf16x8 kf0 = *(const bf16x8*)&KlB[(16 * f + lr) * 128 + ((lg * 16) ^ swl)];
      bf16x8 kf1 = *(const bf16x8*)&KlB[(16 * f + lr) * 128 + ((64 + lg * 16) ^ swl)];
      s = __builtin_amdgcn_mfma_f32_16x16x32_bf16(kf0, qf[0], s, 0, 0, 0);
      s = __builtin_amdgcn_mfma_f32_16x16x32_bf16(kf1, qf[1], s, 0, 0, 0);
      sv4[f] = s;
    }
    __builtin_amdgcn_s_setprio(0);

    float part = 0.f;
    #pragma unroll
    for (int f = 0; f < 4; f++) {
      unsigned nib = (unsigned)(mw >> (16 * f + 4 * lg)) & 0xFu;
      float pv[4];
      #pragma unroll
      for (int r = 0; r < 4; r++) {
        float s = ((nib >> r) & 1u) ? -30000.f : sv4[f][r];
        pv[r] = __builtin_amdgcn_exp2f(s);
        part += pv[r];
      }
      unsigned w0, w1;
      asm("v_cvt_pk_bf16_f32 %0, %1, %2" : "=v"(w0) : "v"(pv[0]), "v"(pv[1]));
      asm("v_cvt_pk_bf16_f32 %0, %1, %2" : "=v"(w1) : "v"(pv[2]), "v"(pv[3]));
      *(uint2*)&PlB[lr * 128 + ((f * 32 + lg * 8) ^ swl)] = make_uint2(w0, w1);
    }
    lsum += part;
    asm volatile("s_waitcnt lgkmcnt(0)" ::: "memory");
    __builtin_amdgcn_sched_barrier(0);

    bf16x8 pf0 = *(const bf16x8*)&PlB[lr * 128 + ((lg * 16) ^ swl)];
    bf16x8 pf1 = *(const bf16x8*)&PlB[lr * 128 + ((64 + lg * 16) ^ swl)];
    __builtin_amdgcn_s_setprio(1);
    #pragma unroll
    for (int f = 0; f < 4; f++) {
      bf16x8 vf0 = *(const bf16x8*)&VlB[(16 * f + lr) * 128 + ((lg * 16) ^ swl)];
      o[f] = __builtin_amdgcn_mfma_f32_16x16x32_bf16(vf0, pf0, o[f], 0, 0, 0);
      bf16x8 vf1 = *(const bf16x8*)&VlB[(16 * f + lr) * 128 + ((64 + lg * 16) ^ swl)];
      o[f] = __builtin_amdgcn_mfma_f32_16x16x32_bf16(vf1, pf1, o[f], 0, 0, 0);
    }
    __builtin_amdgcn_s_setprio(0);
  }

  lsum += __shfl_xor(lsum, 16);
  lsum += __shfl_xor(lsum, 32);
  float inv = 1.f / fmaxf(lsum, 1e-30f);
  #pragma unroll
  for (int f = 0; f < 4; f++) {
    unsigned w0, w1;
    float a0 = o[f][0] * inv, a1 = o[f][1] * inv;
    float a2 = o[f][2] * inv, a3 = o[f][3] * inv;
    asm("v_cvt_pk_bf16_f32 %0, %1, %2" : "=v"(w0) : "v"(a0), "v"(a1));
    asm("v_cvt_pk_bf16_f32 %0, %1, %2" : "=v"(w1) : "v"(a2), "v"(a3));
    *(uint2*)&x[((size_t)b * NN + qrow) * DD + h * DH + 16 * f + lg * 4] =
        make_uint2(w0, w1);
  }
}

extern "C" void kernel_launch(void* const* d_in, const int* in_sizes, int n_in,
                              void* d_out, int out_size, void* d_ws, size_t ws_size,
                              hipStream_t stream) {
  const float* q  = (const float*)d_in[0];
  const float* k  = (const float*)d_in[1];
  const float* v  = (const float*)d_in[2];
  const void*  mk = d_in[3];
  const float* Wq = (const float*)d_in[4];
  const float* bq = (const float*)d_in[5];
  const float* Wk = (const float*)d_in[6];
  const float* bk = (const float*)d_in[7];
  const float* Wv = (const float*)d_in[8];
  const float* bv = (const float*)d_in[9];
  const float* Wp = (const float*)d_in[10];
  const float* bp = (const float*)d_in[11];
  float* out = (float*)d_out;
  char* ws = (char*)d_ws;

  unsigned long long* packed = (unsigned long long*)(ws + OFF_PACK);
  unsigned short* wt  = (unsigned short*)(ws + OFF_WT);
  unsigned short* qhp = (unsigned short*)(ws + OFF_QH);
  unsigned short* khp = (unsigned short*)(ws + OFF_KH);
  unsigned short* vht = (unsigned short*)(ws + OFF_VT);
  unsigned short* x   = (unsigned short*)(ws + OFF_X);
  unsigned short* qb  = (unsigned short*)(ws + OFF_X);  // alias: dead before attn
  unsigned short* kb  = (unsigned short*)(ws + OFF_KB);
  unsigned short* vb  = (unsigned short*)(ws + OFF_VB);

  const bool big = ws_size >= NEED_BIG;

  prep<<<dim3(7680), 256, 0, stream>>>(Wq, Wk, Wv, Wp, wt, q, k, v,
                                       qb, kb, vb, big ? 1 : 0, mk, packed);
  if (big) {
    gemm_pl<0><<<dim3(768), 256, 0, stream>>>(qb, kb, vb, wt,
                                              bq, bk, bv, bp,
                                              qhp, khp, vht, nullptr);
  } else {
    gemm_qkv_f32<<<dim3(8, 32, 3), 256, 0, stream>>>(q, k, v, wt, bq, bk, bv,
                                                     qhp, khp, vht);
  }
  attn_k<<<dim3(1024), 256, 0, stream>>>(qhp, khp, vht, packed, x);
  gemm_pl<1><<<dim3(256), 256, 0, stream>>>(x, nullptr, nullptr, wt,
                                            bq, bk, bv, bp,
                                            nullptr, nullptr, nullptr, out);
}